// Round 1
// baseline (48608.521 us; speedup 1.0000x reference)
//
#include <hip/hip_runtime.h>

// residual_LSTM: B=32, T=1024, H=C=512, L=2, fp32.
// Persistent cooperative kernel: 256 WGs x 256 threads, one WG per (layer, 4 channels).
// Layer-pipelined: tick s -> layer0 computes t=s, layer1 computes t=s-1 => 1 barrier/tick.
// Weights LDS-stationary (64KB, XOR-swizzled). Cell state in registers. All fp32.

typedef unsigned int uint32;

constexpr int B = 32, T = 1024, H = 512, NL = 2;
constexpr int FOURH = 4 * H;
constexpr size_t BTH = (size_t)B * T * H;          // 16777216
constexpr size_t BLH = (size_t)B * NL * H;         // 32768

__device__ __forceinline__ float sigm(float v) { return 1.0f / (1.0f + __expf(-v)); }

__launch_bounds__(256, 1)
__global__ void lstm_persist(const float* __restrict__ x,
                             const float* __restrict__ Wi,
                             const float* __restrict__ bi,
                             const float* __restrict__ Ws,
                             const float* __restrict__ bs,
                             float* __restrict__ out,
                             uint32* __restrict__ ctrl,
                             float* __restrict__ h0buf,   // [2][B][H]
                             float* __restrict__ h1buf)   // [2][B][H]
{
    // [mat(Wi/Ws)][16 local rows][512 k], k stored in XOR-swizzled 4-float chunks:
    // chunk_phys = (k>>2) ^ local_row  -> 16-row wave read lands on 8 banks x2 (free).
    __shared__ __align__(16) float lds_w[2 * 16 * 512];   // 65536 B exactly

    const int wg    = blockIdx.x;        // 0..255
    const int tid   = threadIdx.x;       // 0..255
    const int layer = wg & 1;            // interleave layers across XCDs
    const int chb   = (wg >> 1) * 4;     // 4 channels per WG

    // ---- stage weight slice into LDS (once) ----
    for (int i = tid; i < 2 * 16 * 512; i += 256) {
        const int m   = i >> 13;         // 0 = Wi, 1 = Ws
        const int r   = (i >> 9) & 15;   // local row: gate = r>>2, chan = r&3
        const int k   = i & 511;
        const int row = (r >> 2) * H + chb + (r & 3);
        const float* src = (m == 0) ? Wi : Ws;
        const float v = src[((size_t)layer * FOURH + row) * H + k];
        lds_w[(m * 16 + r) * 512 + (((k >> 2) ^ r) << 2) + (k & 3)] = v;
    }

    const int lr = tid & 15;             // local row this thread computes
    const int bp = tid >> 4;             // batch pair 0..15
    const int b0 = bp * 2, b1 = b0 + 1;
    const int grow = (lr >> 2) * H + chb + (lr & 3);
    const float biasv = bi[layer * FOURH + grow] + bs[layer * FOURH + grow];

    const float* wA = &lds_w[lr * 512];          // Wi row (input path)
    const float* wB = &lds_w[(16 + lr) * 512];   // Ws row (recurrent path)

    const int lane  = tid & 63;
    const int sbase = (lane & 48) | (lane & 3);  // lane of gate-0 row, same (bp, chan)

    float c0 = 0.f, c1 = 0.f;   // cell state (meaningful for lr<4 threads)

    uint32* grp  = ctrl;        // 8 group counters
    uint32* root = ctrl + 8;

    __syncthreads();

    for (int s = 0; s <= T; ++s) {
        const int t = (layer == 0) ? s : s - 1;
        if (t >= 0 && t < T) {
            // input operand: layer0 <- x[:,t,:], layer1 <- h0 slot t&1
            const float* pAb = (layer == 0) ? (x + (size_t)t * H)
                                            : (h0buf + (size_t)(t & 1) * B * H);
            const size_t sA  = (layer == 0) ? (size_t)T * H : (size_t)H;
            // recurrent operand: own layer h, slot (t-1)&1 (zero-initialized for t=0)
            const float* pBb = ((layer == 0) ? h0buf : h1buf) + (size_t)((t - 1) & 1) * B * H;

            const float4* pA0 = (const float4*)(pAb + (size_t)b0 * sA);
            const float4* pA1 = (const float4*)(pAb + (size_t)b1 * sA);
            const float4* pB0 = (const float4*)(pBb + b0 * H);
            const float4* pB1 = (const float4*)(pBb + b1 * H);

            float zA0 = 0.f, zB0 = 0.f, zA1 = 0.f, zB1 = 0.f;
            #pragma unroll 4
            for (int kc = 0; kc < 128; ++kc) {
                const int sw = ((kc ^ lr) << 2);
                const float4 wa = *(const float4*)&wA[sw];
                const float4 wb = *(const float4*)&wB[sw];
                const float4 a0 = pA0[kc];
                const float4 a1 = pA1[kc];
                const float4 r0 = pB0[kc];
                const float4 r1 = pB1[kc];
                zA0 += wa.x*a0.x + wa.y*a0.y + wa.z*a0.z + wa.w*a0.w;
                zA1 += wa.x*a1.x + wa.y*a1.y + wa.z*a1.z + wa.w*a1.w;
                zB0 += wb.x*r0.x + wb.y*r0.y + wb.z*r0.z + wb.w*r0.w;
                zB1 += wb.x*r1.x + wb.y*r1.y + wb.z*r1.z + wb.w*r1.w;
            }
            const float z0 = biasv + zA0 + zB0;
            const float z1 = biasv + zA1 + zB1;

            // gather the 4 gate pre-activations for (chan, batch) onto gate-0 threads
            const float zi0 = __shfl(z0, sbase,      64);
            const float zf0 = __shfl(z0, sbase + 4,  64);
            const float zg0 = __shfl(z0, sbase + 8,  64);
            const float zo0 = __shfl(z0, sbase + 12, 64);
            const float zi1 = __shfl(z1, sbase,      64);
            const float zf1 = __shfl(z1, sbase + 4,  64);
            const float zg1 = __shfl(z1, sbase + 8,  64);
            const float zo1 = __shfl(z1, sbase + 12, 64);

            if (lr < 4) {
                const int ch = chb + lr;
                float* hdst = ((layer == 0) ? h0buf : h1buf) + (size_t)(t & 1) * B * H;
                {   // batch b0
                    const float cn = sigm(zi0) * tanhf(zg0) + sigm(zf0) * c0;
                    c0 = cn;
                    const float resid = pAb[(size_t)b0 * sA + ch];   // = layer input (residual)
                    const float hn = sigm(zo0) * tanhf(cn) + resid;
                    hdst[b0 * H + ch] = hn;
                    if (layer == 1) out[((size_t)b0 * T + t) * H + ch] = hn;
                    if (t == T - 1) {
                        out[BTH + ((size_t)b0 * NL + layer) * H + ch] = hn;
                        out[BTH + BLH + ((size_t)b0 * NL + layer) * H + ch] = cn;
                    }
                }
                {   // batch b1
                    const float cn = sigm(zi1) * tanhf(zg1) + sigm(zf1) * c1;
                    c1 = cn;
                    const float resid = pAb[(size_t)b1 * sA + ch];
                    const float hn = sigm(zo1) * tanhf(cn) + resid;
                    hdst[b1 * H + ch] = hn;
                    if (layer == 1) out[((size_t)b1 * T + t) * H + ch] = hn;
                    if (t == T - 1) {
                        out[BTH + ((size_t)b1 * NL + layer) * H + ch] = hn;
                        out[BTH + BLH + ((size_t)b1 * NL + layer) * H + ch] = cn;
                    }
                }
            }
        }

        // ---- device-wide barrier (two-level, monotonic epochs) ----
        __syncthreads();                       // all WG stores complete (into L2)
        if (tid == 0) {
            __threadfence();                   // release: write back L2 -> LLC
            const uint32 epoch = (uint32)s + 1u;
            const uint32 r = atomicAdd(&grp[wg >> 5], 1u);
            if (r == epoch * 32u - 1u) atomicAdd(root, 1u);
            while (__hip_atomic_load(root, __ATOMIC_RELAXED, __HIP_MEMORY_SCOPE_AGENT) < epoch * 8u) {
                __builtin_amdgcn_s_sleep(2);
            }
            __threadfence();                   // acquire: invalidate L1/L2 before next reads
        }
        __syncthreads();
    }
}

extern "C" void kernel_launch(void* const* d_in, const int* in_sizes, int n_in,
                              void* d_out, int out_size, void* d_ws, size_t ws_size,
                              hipStream_t stream) {
    const float* x  = (const float*)d_in[0];
    const float* Wi = (const float*)d_in[1];
    const float* bi = (const float*)d_in[2];
    const float* Ws = (const float*)d_in[3];
    const float* bs = (const float*)d_in[4];
    float* out = (float*)d_out;

    // ws layout: [0..63] barrier counters | pad | @4096: h0[2][B][H] | h1[2][B][H]
    uint32* ctrl = (uint32*)d_ws;
    float* h0 = (float*)((char*)d_ws + 4096);
    float* h1 = h0 + 2 * B * H;
    const size_t zero_bytes = 4096 + (size_t)2 * 2 * B * H * sizeof(float); // 266240

    hipMemsetAsync(d_ws, 0, zero_bytes, stream);   // zero barrier counters + initial h state
    hipLaunchKernelGGL(lstm_persist, dim3(256), dim3(256), 0, stream,
                       x, Wi, bi, Ws, bs, out, ctrl, h0, h1);
}

// Round 2
// 29233.163 us; speedup vs baseline: 1.6628x; 1.6628x over previous
//
#include <hip/hip_runtime.h>

// residual_LSTM: B=32, T=1024, H=C=512, L=2, fp32.
// Persistent cooperative kernel: 256 WGs x 512 threads (8 waves/CU), one WG per (layer, 4 channels).
// Layer-pipelined: tick s -> layer0 computes t=s, layer1 computes t=s-1 => 1 barrier/tick.
// Weights LDS-stationary (64KB, XOR-swizzled, round-1 verified conflict-free).
// R2: 4-batch register blocking, k-split-by-4 + shfl_xor reduce, release/acquire split fences,
//     spread barrier counters.

typedef unsigned int uint32;

constexpr int B = 32, T = 1024, H = 512, NL = 2;
constexpr int FOURH = 4 * H;
constexpr size_t BTH = (size_t)B * T * H;          // 16777216
constexpr size_t BLH = (size_t)B * NL * H;         // 32768

__device__ __forceinline__ float sigm(float v) { return 1.0f / (1.0f + __expf(-v)); }

__launch_bounds__(512, 1)
__global__ void lstm_persist(const float* __restrict__ x,
                             const float* __restrict__ Wi,
                             const float* __restrict__ bi,
                             const float* __restrict__ Ws,
                             const float* __restrict__ bs,
                             float* __restrict__ out,
                             uint32* __restrict__ ctrl,
                             float* __restrict__ h0buf,   // [2][B][H]
                             float* __restrict__ h1buf)   // [2][B][H]
{
    // [mat][16 rows][512 k], float4 chunk at phys = (k>>2) ^ row  (conflict-free, measured R1)
    __shared__ __align__(16) float lds_w[2 * 16 * 512];   // 65536 B

    const int wg    = blockIdx.x;        // 0..255
    const int tid   = threadIdx.x;       // 0..511
    const int layer = wg & 1;
    const int chb   = (wg >> 1) * 4;     // 4 channels per WG

    // ---- stage weight slice into LDS (once) ----
    for (int i = tid; i < 2 * 16 * 512; i += 512) {
        const int m   = i >> 13;         // 0 = Wi, 1 = Ws
        const int r   = (i >> 9) & 15;   // gate = r>>2, chan = r&3
        const int k   = i & 511;
        const int row = (r >> 2) * H + chb + (r & 3);
        const float* src = (m == 0) ? Wi : Ws;
        const float v = src[((size_t)layer * FOURH + row) * H + k];
        lds_w[(m * 16 + r) * 512 + (((k >> 2) ^ r) << 2) + (k & 3)] = v;
    }

    const int lr = tid & 15;             // local row
    const int ks = (tid >> 4) & 3;       // k-slice (128 k's)
    const int bq = tid >> 6;             // wave id = batch quad
    const int b0 = bq * 4;

    const int grow  = (lr >> 2) * H + chb + (lr & 3);
    const float biasv = bi[layer * FOURH + grow] + bs[layer * FOURH + grow];

    const float* wArow = &lds_w[lr * 512];
    const float* wBrow = &lds_w[(16 + lr) * 512];

    const int lane  = tid & 63;
    const int sbase = lane & 0x33;       // same chan+ks, gate 0

    float c[4] = {0.f, 0.f, 0.f, 0.f};   // cell state (designated threads only)

    uint32* root = ctrl + 256;

    __syncthreads();

    for (int s = 0; s <= T; ++s) {
        const int t = (layer == 0) ? s : s - 1;
        if (t >= 0 && t < T) {
            const float* pAb = (layer == 0) ? (x + (size_t)t * H)
                                            : (h0buf + (size_t)(t & 1) * B * H);
            const size_t sA  = (layer == 0) ? (size_t)T * H : (size_t)H;
            const float* pBb = ((layer == 0) ? h0buf : h1buf) + (size_t)((t - 1) & 1) * B * H;

            const float4* pA0 = (const float4*)(pAb + (size_t)(b0 + 0) * sA) + ks * 32;
            const float4* pA1 = (const float4*)(pAb + (size_t)(b0 + 1) * sA) + ks * 32;
            const float4* pA2 = (const float4*)(pAb + (size_t)(b0 + 2) * sA) + ks * 32;
            const float4* pA3 = (const float4*)(pAb + (size_t)(b0 + 3) * sA) + ks * 32;
            const float4* pB0 = (const float4*)(pBb + (b0 + 0) * H) + ks * 32;
            const float4* pB1 = (const float4*)(pBb + (b0 + 1) * H) + ks * 32;
            const float4* pB2 = (const float4*)(pBb + (b0 + 2) * H) + ks * 32;
            const float4* pB3 = (const float4*)(pBb + (b0 + 3) * H) + ks * 32;

            float z0 = 0.f, z1 = 0.f, z2 = 0.f, z3 = 0.f;     // A-path accum per batch
            float y0 = 0.f, y1 = 0.f, y2 = 0.f, y3 = 0.f;     // B-path accum per batch
            #pragma unroll 2
            for (int kc = 0; kc < 32; ++kc) {
                const int cg = ((ks * 32 + kc) ^ lr) << 2;
                const float4 wa = *(const float4*)&wArow[cg];
                const float4 wb = *(const float4*)&wBrow[cg];
                const float4 a0 = pA0[kc], a1 = pA1[kc], a2 = pA2[kc], a3 = pA3[kc];
                const float4 r0 = pB0[kc], r1 = pB1[kc], r2 = pB2[kc], r3 = pB3[kc];
                z0 += wa.x*a0.x + wa.y*a0.y + wa.z*a0.z + wa.w*a0.w;
                z1 += wa.x*a1.x + wa.y*a1.y + wa.z*a1.z + wa.w*a1.w;
                z2 += wa.x*a2.x + wa.y*a2.y + wa.z*a2.z + wa.w*a2.w;
                z3 += wa.x*a3.x + wa.y*a3.y + wa.z*a3.z + wa.w*a3.w;
                y0 += wb.x*r0.x + wb.y*r0.y + wb.z*r0.z + wb.w*r0.w;
                y1 += wb.x*r1.x + wb.y*r1.y + wb.z*r1.z + wb.w*r1.w;
                y2 += wb.x*r2.x + wb.y*r2.y + wb.z*r2.z + wb.w*r2.w;
                y3 += wb.x*r3.x + wb.y*r3.y + wb.z*r3.z + wb.w*r3.w;
            }
            z0 += y0; z1 += y1; z2 += y2; z3 += y3;
            // reduce over the 4 k-slices (lane bits 4,5)
            z0 += __shfl_xor(z0, 16); z0 += __shfl_xor(z0, 32);
            z1 += __shfl_xor(z1, 16); z1 += __shfl_xor(z1, 32);
            z2 += __shfl_xor(z2, 16); z2 += __shfl_xor(z2, 32);
            z3 += __shfl_xor(z3, 16); z3 += __shfl_xor(z3, 32);
            z0 += biasv; z1 += biasv; z2 += biasv; z3 += biasv;

            float zz[4] = {z0, z1, z2, z3};
            float zi[4], zf[4], zg[4], zo[4];
            #pragma unroll
            for (int j = 0; j < 4; ++j) {
                zi[j] = __shfl(zz[j], sbase);
                zf[j] = __shfl(zz[j], sbase | 4);
                zg[j] = __shfl(zz[j], sbase | 8);
                zo[j] = __shfl(zz[j], sbase | 12);
            }

            if ((lane & 63) < 4) {        // lr<4 && ks==0: owns chan chb+lr, batches b0..b0+3
                const int ch = chb + lr;
                float* hdst = ((layer == 0) ? h0buf : h1buf) + (size_t)(t & 1) * B * H;
                #pragma unroll
                for (int j = 0; j < 4; ++j) {
                    const int b = b0 + j;
                    const float cn = sigm(zi[j]) * tanhf(zg[j]) + sigm(zf[j]) * c[j];
                    c[j] = cn;
                    const float resid = pAb[(size_t)b * sA + ch];
                    const float hn = sigm(zo[j]) * tanhf(cn) + resid;
                    hdst[b * H + ch] = hn;
                    if (layer == 1) out[((size_t)b * T + t) * H + ch] = hn;
                    if (t == T - 1) {
                        out[BTH + ((size_t)b * NL + layer) * H + ch] = hn;
                        out[BTH + BLH + ((size_t)b * NL + layer) * H + ch] = cn;
                    }
                }
            }
        }

        // ---- device-wide barrier (two-level, monotonic epochs, split fences) ----
        __syncthreads();                   // all waves drain stores (vmcnt) before barrier
        if (tid == 0) {
            __builtin_amdgcn_fence(__ATOMIC_RELEASE, "agent");   // wb L2 -> LLC
            const uint32 epoch = (uint32)s + 1u;
            uint32* gcnt = ctrl + (wg >> 5) * 32;                // 128B-spread counters
            const uint32 r = __hip_atomic_fetch_add(gcnt, 1u, __ATOMIC_RELAXED,
                                                    __HIP_MEMORY_SCOPE_AGENT);
            if (r == epoch * 32u - 1u)
                __hip_atomic_fetch_add(root, 1u, __ATOMIC_RELAXED, __HIP_MEMORY_SCOPE_AGENT);
            while (__hip_atomic_load(root, __ATOMIC_RELAXED, __HIP_MEMORY_SCOPE_AGENT) < epoch * 8u) {
                __builtin_amdgcn_s_sleep(2);
            }
            __builtin_amdgcn_fence(__ATOMIC_ACQUIRE, "agent");   // inv L1/L2
        }
        __syncthreads();
    }
}

extern "C" void kernel_launch(void* const* d_in, const int* in_sizes, int n_in,
                              void* d_out, int out_size, void* d_ws, size_t ws_size,
                              hipStream_t stream) {
    const float* x  = (const float*)d_in[0];
    const float* Wi = (const float*)d_in[1];
    const float* bi = (const float*)d_in[2];
    const float* Ws = (const float*)d_in[3];
    const float* bs = (const float*)d_in[4];
    float* out = (float*)d_out;

    // ws layout: [0..1023] dwords barrier counters (spread) | @4096: h0[2][B][H] | h1[2][B][H]
    uint32* ctrl = (uint32*)d_ws;
    float* h0 = (float*)((char*)d_ws + 4096);
    float* h1 = h0 + 2 * B * H;
    const size_t zero_bytes = 4096 + (size_t)2 * 2 * B * H * sizeof(float);

    hipMemsetAsync(d_ws, 0, zero_bytes, stream);
    hipLaunchKernelGGL(lstm_persist, dim3(256), dim3(512), 0, stream,
                       x, Wi, bi, Ws, bs, out, ctrl, h0, h1);
}

// Round 3
// 17643.251 us; speedup vs baseline: 2.7551x; 1.6569x over previous
//
#include <hip/hip_runtime.h>

// residual_LSTM: B=32, T=1024, H=C=512, L=2, fp32 in/out.
// R3: MFMA restructure. Persistent 256 WGs x 512 threads, WG = (layer, 16 z-rows = 4 gates x 4 ch).
// Per tick: z[16,32] = [Wi|Ws](16,1024) @ [x;h](1024,32) via mfma_f32_16x16x32_bf16,
// split-precision (hi+lo): z = Ahi*Whi + Alo*Whi + Ahi*Wlo  (~fp32 accuracy).
// Weights hi/lo in LDS (64KB, XOR-swizzled 16B chunks, conflict-free). h exchanged as
// pre-split bf16 hi/lo global buffers. 8 waves = 2 M-tiles x 4 k-quarters; k-reduction
// via 8KB LDS. Device barrier = R2-validated two-level atomic w/ split fences.

typedef unsigned int uint32;
typedef unsigned short ushort;

constexpr int B = 32, T = 1024, H = 512, NL = 2;
constexpr int KTOT = 2 * H;            // 1024 (combined [x;h] k-dim)
constexpr int BH   = B * H;            // 16384
constexpr size_t BTH = (size_t)B * T * H;
constexpr size_t BLH = (size_t)B * NL * H;

using bf16x8  = __attribute__((ext_vector_type(8))) short;
using floatx4 = __attribute__((ext_vector_type(4))) float;

__device__ __forceinline__ float sigm(float v) { return 1.0f / (1.0f + __expf(-v)); }

__device__ __forceinline__ ushort f2bf(float f) {        // RNE fp32 -> bf16 bits
    uint32 u = __builtin_bit_cast(uint32, f);
    u += 0x7fffu + ((u >> 16) & 1u);
    return (ushort)(u >> 16);
}

__launch_bounds__(512, 1)
__global__ void lstm_persist(const float* __restrict__ x,
                             const float* __restrict__ Wi,
                             const float* __restrict__ bi,
                             const float* __restrict__ Ws,
                             const float* __restrict__ bs,
                             float* __restrict__ out,
                             uint32* __restrict__ ctrl,
                             float*  __restrict__ h0f,    // [2][B][H] fp32 (residual for layer1)
                             ushort* __restrict__ h0hi, ushort* __restrict__ h0lo,
                             ushort* __restrict__ h1hi, ushort* __restrict__ h1lo)
{
    extern __shared__ short smem[];
    short* whi = smem;                       // [16 rows][1024 k] bf16, swizzled 16B chunks
    short* wlo = smem + 16 * KTOT;           // same layout
    float* red = (float*)(smem + 32 * KTOT); // [8 waves][64 lanes][4 regs] fp32 (8KB)

    const int wg    = blockIdx.x;            // 0..255
    const int tid   = threadIdx.x;           // 0..511
    const int layer = wg & 1;
    const int rg    = wg >> 1;               // row-group 0..127
    const int chb   = rg * 4;                // 4 channels per WG

    // ---- stage + hi/lo split weights into LDS (once). local row n = gate*4 + c ----
    for (int i = tid; i < 16 * KTOT; i += 512) {
        const int n = i >> 10, k = i & (KTOT - 1);
        const int g = n >> 2, c = n & 3;
        const int grow = g * H + chb + c;
        const float v = (k < H) ? Wi[((size_t)layer * 4 * H + grow) * H + k]
                                : Ws[((size_t)layer * 4 * H + grow) * H + (k - H)];
        const ushort hb = f2bf(v);
        const float  hf = __builtin_bit_cast(float, (uint32)hb << 16);
        const ushort lb = f2bf(v - hf);      // exact residual (Sterbenz), then RNE
        const int off = (n * 128 + ((k >> 3) ^ n)) * 8 + (k & 7);   // XOR chunk swizzle
        whi[off] = (short)hb;
        wlo[off] = (short)lb;
    }

    const int lane = tid & 63;
    const int w    = tid >> 6;               // wave 0..7
    const int mt   = w & 1;                  // M-tile (batches mt*16..mt*16+15)
    const int kq   = w >> 1;                 // k-quarter (256 k each)
    const int quad = lane >> 4;              // A/B frag k-subblock
    const int mrow = lane & 15;
    const int bb   = mt * 16 + mrow;         // this lane's batch in A-frag
    const int nn   = mrow;                   // this lane's row in B-frag

    // ---- epilogue thread state: (c = tid&3, b = tid>>2) for tid<128 ----
    const int ec = tid & 3, eb = tid >> 2;
    float cs = 0.f;                          // cell state register
    float bias_[4] = {0.f, 0.f, 0.f, 0.f};
    if (tid < 128) {
        #pragma unroll
        for (int g = 0; g < 4; ++g) {
            const int grow = g * H + chb + ec;
            bias_[g] = bi[layer * 4 * H + grow] + bs[layer * 4 * H + grow];
        }
    }

    uint32* root = ctrl + 256;
    __syncthreads();

    for (int s = 0; s <= T; ++s) {
        const int t = (layer == 0) ? s : s - 1;
        const bool active = (t >= 0 && t < T);
        if (active) {
            floatx4 acc0 = {0.f, 0.f, 0.f, 0.f};
            floatx4 acc1 = {0.f, 0.f, 0.f, 0.f};

            if (layer == 0 && kq < 2) {
                // x path: fp32 loads + on-the-fly hi/lo split
                const float* xb = x + ((size_t)bb * T + t) * H + kq * 256 + quad * 8;
                #pragma unroll
                for (int st = 0; st < 8; ++st) {
                    const float4* p = (const float4*)(xb + st * 32);
                    const float4 f0 = p[0], f1 = p[1];
                    const float vv[8] = {f0.x, f0.y, f0.z, f0.w, f1.x, f1.y, f1.z, f1.w};
                    bf16x8 ahi, alo;
                    #pragma unroll
                    for (int j = 0; j < 8; ++j) {
                        const ushort hb = f2bf(vv[j]);
                        const float  hf = __builtin_bit_cast(float, (uint32)hb << 16);
                        ahi[j] = (short)hb;
                        alo[j] = (short)f2bf(vv[j] - hf);
                    }
                    const int cb = kq * 32 + st * 4 + quad;
                    const int woff = (nn * 128 + (cb ^ nn)) * 8;
                    const bf16x8 bh = *(const bf16x8*)(whi + woff);
                    const bf16x8 bl = *(const bf16x8*)(wlo + woff);
                    acc0 = __builtin_amdgcn_mfma_f32_16x16x32_bf16(ahi, bh, acc0, 0, 0, 0);
                    acc1 = __builtin_amdgcn_mfma_f32_16x16x32_bf16(alo, bh, acc1, 0, 0, 0);
                    acc1 = __builtin_amdgcn_mfma_f32_16x16x32_bf16(ahi, bl, acc1, 0, 0, 0);
                }
            } else {
                // h path: pre-split bf16 hi/lo loads
                int par, koff;
                const ushort *bhB, *blB;
                if (layer == 0)   { par = (t - 1) & 1; koff = kq * 256 - 512; bhB = h0hi; blB = h0lo; }
                else if (kq < 2)  { par = t & 1;       koff = kq * 256;       bhB = h0hi; blB = h0lo; }
                else              { par = (t - 1) & 1; koff = kq * 256 - 512; bhB = h1hi; blB = h1lo; }
                const size_t base = (size_t)par * BH + (size_t)bb * H + koff + quad * 8;
                const ushort* ph = bhB + base;
                const ushort* pl = blB + base;
                #pragma unroll
                for (int st = 0; st < 8; ++st) {
                    const bf16x8 ahi = *(const bf16x8*)(ph + st * 32);
                    const bf16x8 alo = *(const bf16x8*)(pl + st * 32);
                    const int cb = kq * 32 + st * 4 + quad;
                    const int woff = (nn * 128 + (cb ^ nn)) * 8;
                    const bf16x8 bh = *(const bf16x8*)(whi + woff);
                    const bf16x8 bl = *(const bf16x8*)(wlo + woff);
                    acc0 = __builtin_amdgcn_mfma_f32_16x16x32_bf16(ahi, bh, acc0, 0, 0, 0);
                    acc1 = __builtin_amdgcn_mfma_f32_16x16x32_bf16(alo, bh, acc1, 0, 0, 0);
                    acc1 = __builtin_amdgcn_mfma_f32_16x16x32_bf16(ahi, bl, acc1, 0, 0, 0);
                }
            }
            floatx4 zr;
            zr[0] = acc0[0] + acc1[0]; zr[1] = acc0[1] + acc1[1];
            zr[2] = acc0[2] + acc1[2]; zr[3] = acc0[3] + acc1[3];
            *(floatx4*)&red[((w * 64) + lane) * 4] = zr;   // contiguous b128, conflict-free
        }
        __syncthreads();   // red visible to epilogue

        if (active && tid < 128) {
            // D layout (m89): n = lane&15, m = (lane>>4)*4 + reg
            const int m = eb & 15, emt = eb >> 4, q = m >> 2, r = m & 3;
            const int ch = chb + ec;
            float z[4];
            #pragma unroll
            for (int g = 0; g < 4; ++g) {
                const int li = q * 16 + (g * 4 + ec);
                float a = bias_[g];
                #pragma unroll
                for (int kqe = 0; kqe < 4; ++kqe)
                    a += red[((kqe * 2 + emt) * 64 + li) * 4 + r];
                z[g] = a;
            }
            const float ig = sigm(z[0]), fg = sigm(z[1]);
            const float gg = tanhf(z[2]), og = sigm(z[3]);
            cs = ig * gg + fg * cs;
            const float resid = (layer == 0) ? x[((size_t)eb * T + t) * H + ch]
                                             : h0f[(size_t)(t & 1) * BH + eb * H + ch];
            const float hn = og * tanhf(cs) + resid;

            const size_t hidx = (size_t)(t & 1) * BH + (size_t)eb * H + ch;
            const ushort hb = f2bf(hn);
            const float  hf = __builtin_bit_cast(float, (uint32)hb << 16);
            const ushort lb = f2bf(hn - hf);
            if (layer == 0) {
                h0f[hidx] = hn; h0hi[hidx] = hb; h0lo[hidx] = lb;
            } else {
                h1hi[hidx] = hb; h1lo[hidx] = lb;
                out[((size_t)eb * T + t) * H + ch] = hn;
            }
            if (t == T - 1) {
                out[BTH + ((size_t)eb * NL + layer) * H + ch] = hn;
                out[BTH + BLH + ((size_t)eb * NL + layer) * H + ch] = cs;
            }
        }

        // ---- device-wide barrier (two-level, monotonic epochs, split fences) ----
        __syncthreads();
        if (tid == 0) {
            __builtin_amdgcn_fence(__ATOMIC_RELEASE, "agent");
            const uint32 epoch = (uint32)s + 1u;
            uint32* gcnt = ctrl + (wg >> 5) * 32;
            const uint32 rr = __hip_atomic_fetch_add(gcnt, 1u, __ATOMIC_RELAXED,
                                                     __HIP_MEMORY_SCOPE_AGENT);
            if (rr == epoch * 32u - 1u)
                __hip_atomic_fetch_add(root, 1u, __ATOMIC_RELAXED, __HIP_MEMORY_SCOPE_AGENT);
            while (__hip_atomic_load(root, __ATOMIC_RELAXED, __HIP_MEMORY_SCOPE_AGENT) < epoch * 8u)
                __builtin_amdgcn_s_sleep(2);
            __builtin_amdgcn_fence(__ATOMIC_ACQUIRE, "agent");
        }
        __syncthreads();
    }
}

extern "C" void kernel_launch(void* const* d_in, const int* in_sizes, int n_in,
                              void* d_out, int out_size, void* d_ws, size_t ws_size,
                              hipStream_t stream) {
    const float* x  = (const float*)d_in[0];
    const float* Wi = (const float*)d_in[1];
    const float* bi = (const float*)d_in[2];
    const float* Ws = (const float*)d_in[3];
    const float* bs = (const float*)d_in[4];
    float* out = (float*)d_out;

    // ws layout: ctrl 4KB | h0f fp32 [2][B][H] 128KB | h0hi/h0lo/h1hi/h1lo bf16 [2][B][H] 64KB each
    char* wsb = (char*)d_ws;
    uint32* ctrl = (uint32*)wsb;
    float*  h0f  = (float*)(wsb + 4096);
    ushort* h0hi = (ushort*)(wsb + 4096 + 131072);
    ushort* h0lo = h0hi + 2 * BH;
    ushort* h1hi = h0lo + 2 * BH;
    ushort* h1lo = h1hi + 2 * BH;
    const size_t zero_bytes = 4096 + 131072 + 4 * (size_t)(2 * BH) * sizeof(ushort); // 397312

    static const size_t lds_bytes = (size_t)(32 * KTOT) * sizeof(short) + 8 * 64 * 4 * sizeof(float); // 73728
    hipFuncSetAttribute((const void*)lstm_persist,
                        hipFuncAttributeMaxDynamicSharedMemorySize, (int)lds_bytes);

    hipMemsetAsync(d_ws, 0, zero_bytes, stream);
    hipLaunchKernelGGL(lstm_persist, dim3(256), dim3(512), lds_bytes, stream,
                       x, Wi, bi, Ws, bs, out, ctrl, h0f, h0hi, h0lo, h1hi, h1lo);
}

// Round 4
// 9831.063 us; speedup vs baseline: 4.9444x; 1.7946x over previous
//
#include <hip/hip_runtime.h>

// residual_LSTM: B=32, T=1024, H=C=512, L=2, fp32 in/out.
// R4: fine-grained LLC coherence. h exchanged as packed (bf16hi | bf16lo<<16) uint32
// buffers, written with relaxed agent-scope atomic stores (global_store sc0 sc1,
// write-through to LLC) and read with inline-asm global_load_dwordx4 sc0 sc1 batches
// (single vmcnt wait). NO agent fences -> no buffer_wbl2 / buffer_inv, L2 stays warm.
// Everything else: R3-verified MFMA structure (split-precision bf16 hi/lo, LDS-resident
// swizzled weights, 8 waves = 2 M-tiles x 4 k-quarters, LDS k-reduction, two-level
// atomic device barrier).

typedef unsigned int uint32;
typedef unsigned short ushort;

constexpr int B = 32, T = 1024, H = 512, NL = 2;
constexpr int KTOT = 2 * H;            // 1024 (combined [x;h] k-dim)
constexpr int BH   = B * H;            // 16384
constexpr size_t BTH = (size_t)B * T * H;
constexpr size_t BLH = (size_t)B * NL * H;

using bf16x8  = __attribute__((ext_vector_type(8))) short;
using floatx4 = __attribute__((ext_vector_type(4))) float;
using uint4v  = __attribute__((ext_vector_type(4))) uint32;

__device__ __forceinline__ float sigm(float v) { return 1.0f / (1.0f + __expf(-v)); }

__device__ __forceinline__ ushort f2bf(float f) {        // RNE fp32 -> bf16 bits
    uint32 u = __builtin_bit_cast(uint32, f);
    u += 0x7fffu + ((u >> 16) & 1u);
    return (ushort)(u >> 16);
}

__launch_bounds__(512, 1)
__global__ void lstm_persist(const float* __restrict__ x,
                             const float* __restrict__ Wi,
                             const float* __restrict__ bi,
                             const float* __restrict__ Ws,
                             const float* __restrict__ bs,
                             float* __restrict__ out,
                             uint32* __restrict__ ctrl,
                             float*  __restrict__ h0f,    // [2][B][H] fp32 (residual for layer1)
                             uint32* __restrict__ h0pk,   // [2][B][H] packed hi|lo<<16
                             uint32* __restrict__ h1pk)
{
    extern __shared__ short smem[];
    short* whi = smem;                       // [16 rows][1024 k] bf16, swizzled 16B chunks
    short* wlo = smem + 16 * KTOT;
    float* red = (float*)(smem + 32 * KTOT); // [8 waves][64 lanes][4 regs] fp32 (8KB)

    const int wg    = blockIdx.x;            // 0..255
    const int tid   = threadIdx.x;           // 0..511
    const int layer = wg & 1;
    const int rg    = wg >> 1;               // row-group 0..127
    const int chb   = rg * 4;                // 4 channels per WG

    // ---- stage + hi/lo split weights into LDS (once). local row n = gate*4 + c ----
    for (int i = tid; i < 16 * KTOT; i += 512) {
        const int n = i >> 10, k = i & (KTOT - 1);
        const int g = n >> 2, c = n & 3;
        const int grow = g * H + chb + c;
        const float v = (k < H) ? Wi[((size_t)layer * 4 * H + grow) * H + k]
                                : Ws[((size_t)layer * 4 * H + grow) * H + (k - H)];
        const ushort hb = f2bf(v);
        const float  hf = __builtin_bit_cast(float, (uint32)hb << 16);
        const ushort lb = f2bf(v - hf);
        const int off = (n * 128 + ((k >> 3) ^ n)) * 8 + (k & 7);   // XOR chunk swizzle
        whi[off] = (short)hb;
        wlo[off] = (short)lb;
    }

    const int lane = tid & 63;
    const int w    = tid >> 6;               // wave 0..7
    const int mt   = w & 1;                  // M-tile (batches mt*16..mt*16+15)
    const int kq   = w >> 1;                 // k-quarter (256 k each)
    const int quad = lane >> 4;
    const int mrow = lane & 15;
    const int bb   = mt * 16 + mrow;         // this lane's batch in A-frag
    const int nn   = mrow;                   // this lane's row in B-frag

    const int ec = tid & 3, eb = tid >> 2;   // epilogue mapping (tid < 128)
    float cs = 0.f;
    float bias_[4] = {0.f, 0.f, 0.f, 0.f};
    if (tid < 128) {
        #pragma unroll
        for (int g = 0; g < 4; ++g) {
            const int grow = g * H + chb + ec;
            bias_[g] = bi[layer * 4 * H + grow] + bs[layer * 4 * H + grow];
        }
    }

    uint32* root = ctrl + 256;
    __syncthreads();

    for (int s = 0; s <= T; ++s) {
        const int t = (layer == 0) ? s : s - 1;
        const bool active = (t >= 0 && t < T);
        if (active) {
            floatx4 acc0 = {0.f, 0.f, 0.f, 0.f};
            floatx4 acc1 = {0.f, 0.f, 0.f, 0.f};

            if (layer == 0 && kq < 2) {
                // x path: fp32 loads (normal cached; L2 stays warm now) + on-the-fly split
                const float* xb = x + ((size_t)bb * T + t) * H + kq * 256 + quad * 8;
                #pragma unroll
                for (int st = 0; st < 8; ++st) {
                    const float4* p = (const float4*)(xb + st * 32);
                    const float4 f0 = p[0], f1 = p[1];
                    const float vv[8] = {f0.x, f0.y, f0.z, f0.w, f1.x, f1.y, f1.z, f1.w};
                    bf16x8 ahi, alo;
                    #pragma unroll
                    for (int j = 0; j < 8; ++j) {
                        const ushort hb = f2bf(vv[j]);
                        const float  hf = __builtin_bit_cast(float, (uint32)hb << 16);
                        ahi[j] = (short)hb;
                        alo[j] = (short)f2bf(vv[j] - hf);
                    }
                    const int cb = kq * 32 + st * 4 + quad;
                    const int woff = (nn * 128 + (cb ^ nn)) * 8;
                    const bf16x8 bh = *(const bf16x8*)(whi + woff);
                    const bf16x8 bl = *(const bf16x8*)(wlo + woff);
                    acc0 = __builtin_amdgcn_mfma_f32_16x16x32_bf16(ahi, bh, acc0, 0, 0, 0);
                    acc1 = __builtin_amdgcn_mfma_f32_16x16x32_bf16(alo, bh, acc1, 0, 0, 0);
                    acc1 = __builtin_amdgcn_mfma_f32_16x16x32_bf16(ahi, bl, acc1, 0, 0, 0);
                }
            } else {
                // h path: packed coherent loads direct from LLC (sc0 sc1), one vmcnt wait
                int par, koff;
                const uint32* hbuf;
                if (layer == 0)   { par = (t - 1) & 1; koff = kq * 256 - 512; hbuf = h0pk; }
                else if (kq < 2)  { par = t & 1;       koff = kq * 256;       hbuf = h0pk; }
                else              { par = (t - 1) & 1; koff = kq * 256 - 512; hbuf = h1pk; }
                const uint32* hp = hbuf + (size_t)par * BH + (size_t)bb * H + koff + quad * 8;

                uint4v q0,q1,q2,q3,q4,q5,q6,q7,q8,q9,q10,q11,q12,q13,q14,q15;
                asm volatile(
                    "global_load_dwordx4 %0,  %16, off sc0 sc1\n\t"
                    "global_load_dwordx4 %1,  %16, off offset:16 sc0 sc1\n\t"
                    "global_load_dwordx4 %2,  %16, off offset:128 sc0 sc1\n\t"
                    "global_load_dwordx4 %3,  %16, off offset:144 sc0 sc1\n\t"
                    "global_load_dwordx4 %4,  %16, off offset:256 sc0 sc1\n\t"
                    "global_load_dwordx4 %5,  %16, off offset:272 sc0 sc1\n\t"
                    "global_load_dwordx4 %6,  %16, off offset:384 sc0 sc1\n\t"
                    "global_load_dwordx4 %7,  %16, off offset:400 sc0 sc1\n\t"
                    "global_load_dwordx4 %8,  %16, off offset:512 sc0 sc1\n\t"
                    "global_load_dwordx4 %9,  %16, off offset:528 sc0 sc1\n\t"
                    "global_load_dwordx4 %10, %16, off offset:640 sc0 sc1\n\t"
                    "global_load_dwordx4 %11, %16, off offset:656 sc0 sc1\n\t"
                    "global_load_dwordx4 %12, %16, off offset:768 sc0 sc1\n\t"
                    "global_load_dwordx4 %13, %16, off offset:784 sc0 sc1\n\t"
                    "global_load_dwordx4 %14, %16, off offset:896 sc0 sc1\n\t"
                    "global_load_dwordx4 %15, %16, off offset:912 sc0 sc1\n\t"
                    "s_waitcnt vmcnt(0)"
                    : "=&v"(q0), "=&v"(q1), "=&v"(q2), "=&v"(q3),
                      "=&v"(q4), "=&v"(q5), "=&v"(q6), "=&v"(q7),
                      "=&v"(q8), "=&v"(q9), "=&v"(q10), "=&v"(q11),
                      "=&v"(q12), "=&v"(q13), "=&v"(q14), "=&v"(q15)
                    : "v"(hp)
                    : "memory");
                const uint4v qq[16] = {q0,q1,q2,q3,q4,q5,q6,q7,q8,q9,q10,q11,q12,q13,q14,q15};

                #pragma unroll
                for (int st = 0; st < 8; ++st) {
                    const uint4v ea = qq[2 * st], eb4 = qq[2 * st + 1];   // elems 0-3, 4-7
                    uint4v hiw, low;
                    hiw[0] = __builtin_amdgcn_perm(ea[1],  ea[0],  0x05040100u);
                    hiw[1] = __builtin_amdgcn_perm(ea[3],  ea[2],  0x05040100u);
                    hiw[2] = __builtin_amdgcn_perm(eb4[1], eb4[0], 0x05040100u);
                    hiw[3] = __builtin_amdgcn_perm(eb4[3], eb4[2], 0x05040100u);
                    low[0] = __builtin_amdgcn_perm(ea[1],  ea[0],  0x07060302u);
                    low[1] = __builtin_amdgcn_perm(ea[3],  ea[2],  0x07060302u);
                    low[2] = __builtin_amdgcn_perm(eb4[1], eb4[0], 0x07060302u);
                    low[3] = __builtin_amdgcn_perm(eb4[3], eb4[2], 0x07060302u);
                    const bf16x8 ahi = __builtin_bit_cast(bf16x8, hiw);
                    const bf16x8 alo = __builtin_bit_cast(bf16x8, low);
                    const int cb = kq * 32 + st * 4 + quad;
                    const int woff = (nn * 128 + (cb ^ nn)) * 8;
                    const bf16x8 bh = *(const bf16x8*)(whi + woff);
                    const bf16x8 bl = *(const bf16x8*)(wlo + woff);
                    acc0 = __builtin_amdgcn_mfma_f32_16x16x32_bf16(ahi, bh, acc0, 0, 0, 0);
                    acc1 = __builtin_amdgcn_mfma_f32_16x16x32_bf16(alo, bh, acc1, 0, 0, 0);
                    acc1 = __builtin_amdgcn_mfma_f32_16x16x32_bf16(ahi, bl, acc1, 0, 0, 0);
                }
            }
            floatx4 zr;
            zr[0] = acc0[0] + acc1[0]; zr[1] = acc0[1] + acc1[1];
            zr[2] = acc0[2] + acc1[2]; zr[3] = acc0[3] + acc1[3];
            *(floatx4*)&red[((w * 64) + lane) * 4] = zr;
        }
        __syncthreads();   // red visible to epilogue

        if (active && tid < 128) {
            // D layout (m89): n = lane&15, m = (lane>>4)*4 + reg
            const int m = eb & 15, emt = eb >> 4, q = m >> 2, r = m & 3;
            const int ch = chb + ec;
            float z[4];
            #pragma unroll
            for (int g = 0; g < 4; ++g) {
                const int li = q * 16 + (g * 4 + ec);
                float a = bias_[g];
                #pragma unroll
                for (int kqe = 0; kqe < 4; ++kqe)
                    a += red[((kqe * 2 + emt) * 64 + li) * 4 + r];
                z[g] = a;
            }
            const float ig = sigm(z[0]), fg = sigm(z[1]);
            const float gg = tanhf(z[2]), og = sigm(z[3]);
            cs = ig * gg + fg * cs;
            const float resid = (layer == 0)
                ? x[((size_t)eb * T + t) * H + ch]
                : __hip_atomic_load(&h0f[(size_t)(t & 1) * BH + eb * H + ch],
                                    __ATOMIC_RELAXED, __HIP_MEMORY_SCOPE_AGENT);
            const float hn = og * tanhf(cs) + resid;

            const size_t hidx = (size_t)(t & 1) * BH + (size_t)eb * H + ch;
            const ushort hb = f2bf(hn);
            const float  hf = __builtin_bit_cast(float, (uint32)hb << 16);
            const ushort lb = f2bf(hn - hf);
            const uint32 pk = (uint32)hb | ((uint32)lb << 16);
            if (layer == 0) {
                __hip_atomic_store(&h0f[hidx], hn, __ATOMIC_RELAXED, __HIP_MEMORY_SCOPE_AGENT);
                __hip_atomic_store(&h0pk[hidx], pk, __ATOMIC_RELAXED, __HIP_MEMORY_SCOPE_AGENT);
            } else {
                __hip_atomic_store(&h1pk[hidx], pk, __ATOMIC_RELAXED, __HIP_MEMORY_SCOPE_AGENT);
                out[((size_t)eb * T + t) * H + ch] = hn;
            }
            if (t == T - 1) {
                out[BTH + ((size_t)eb * NL + layer) * H + ch] = hn;
                out[BTH + BLH + ((size_t)eb * NL + layer) * H + ch] = cs;
            }
        }

        // ---- device-wide barrier: two-level atomics at LLC, NO cache fences.
        // __syncthreads drains each wave's vmcnt -> write-through stores are LLC-visible.
        __syncthreads();
        if (tid == 0) {
            const uint32 epoch = (uint32)s + 1u;
            uint32* gcnt = ctrl + (wg >> 5) * 32;
            const uint32 rr = __hip_atomic_fetch_add(gcnt, 1u, __ATOMIC_RELAXED,
                                                     __HIP_MEMORY_SCOPE_AGENT);
            if (rr == epoch * 32u - 1u)
                __hip_atomic_fetch_add(root, 1u, __ATOMIC_RELAXED, __HIP_MEMORY_SCOPE_AGENT);
            while (__hip_atomic_load(root, __ATOMIC_RELAXED, __HIP_MEMORY_SCOPE_AGENT) < epoch * 8u)
                __builtin_amdgcn_s_sleep(2);
        }
        __syncthreads();
    }
}

extern "C" void kernel_launch(void* const* d_in, const int* in_sizes, int n_in,
                              void* d_out, int out_size, void* d_ws, size_t ws_size,
                              hipStream_t stream) {
    const float* x  = (const float*)d_in[0];
    const float* Wi = (const float*)d_in[1];
    const float* bi = (const float*)d_in[2];
    const float* Ws = (const float*)d_in[3];
    const float* bs = (const float*)d_in[4];
    float* out = (float*)d_out;

    // ws: ctrl 4KB | h0f fp32 [2][B][H] 128KB | h0pk u32 [2][B][H] 128KB | h1pk 128KB
    char* wsb = (char*)d_ws;
    uint32* ctrl = (uint32*)wsb;
    float*  h0f  = (float*)(wsb + 4096);
    uint32* h0pk = (uint32*)(wsb + 4096 + 131072);
    uint32* h1pk = (uint32*)(wsb + 4096 + 2 * 131072);
    const size_t zero_bytes = 4096 + 3 * 131072;   // 397312

    static const size_t lds_bytes = (size_t)(32 * KTOT) * sizeof(short) + 8 * 64 * 4 * sizeof(float); // 73728
    hipFuncSetAttribute((const void*)lstm_persist,
                        hipFuncAttributeMaxDynamicSharedMemorySize, (int)lds_bytes);

    hipMemsetAsync(d_ws, 0, zero_bytes, stream);
    hipLaunchKernelGGL(lstm_persist, dim3(256), dim3(512), lds_bytes, stream,
                       x, Wi, bi, bs ? Ws : Ws, bs, out, ctrl, h0f, h0pk, h1pk);
}